// Round 1
// baseline (693.681 us; speedup 1.0000x reference)
//
#include <hip/hip_runtime.h>
#include <hip/hip_bf16.h>

// B=8, T=2048, E=1024 single-head attention, bf16 MFMA pipeline.
typedef __attribute__((ext_vector_type(8))) short short8;     // MFMA A/B frag (8 bf16)
typedef __attribute__((ext_vector_type(8))) unsigned short ushortx8;
typedef __attribute__((ext_vector_type(4))) unsigned short ushortx4;
typedef __attribute__((ext_vector_type(4))) float floatx4;

#define NB 8
#define NT 2048
#define NE 1024

__device__ __forceinline__ unsigned short f2bf(float f){
  unsigned int u = __builtin_bit_cast(unsigned int, f);
  u += 0x7FFFu + ((u >> 16) & 1u);          // RNE; inputs finite (no NaN)
  return (unsigned short)(u >> 16);
}
__device__ __forceinline__ float bf2f(unsigned short h){
  unsigned int u = ((unsigned int)h) << 16;
  return __builtin_bit_cast(float, u);
}

// ---------------- fp32 -> bf16 convert for the three weight matrices ----------------
__global__ __launch_bounds__(256) void convert3(const float* __restrict__ a0,
                                                const float* __restrict__ a1,
                                                const float* __restrict__ a2,
                                                unsigned short* __restrict__ out,
                                                int n4_per){
  const float* src = blockIdx.z == 0 ? a0 : (blockIdx.z == 1 ? a1 : a2);
  unsigned short* dst = out + (size_t)blockIdx.z * (size_t)n4_per * 4;
  int i = blockIdx.x * 256 + threadIdx.x;
  if (i < n4_per){
    floatx4 f = ((const floatx4*)src)[i];
    ushortx4 o;
    o.x = f2bf(f.x); o.y = f2bf(f.y); o.z = f2bf(f.z); o.w = f2bf(f.w);
    *(ushortx4*)(dst + (size_t)i * 4) = o;
  }
}

// ---------------- shared NT GEMM core: C[m,n] = sum_k A[m,k] * B[n,k] ----------------
// AF32: A is fp32 (converted to bf16 during LDS staging); else A is bf16.
// EPI 0: store bf16.  EPI 1: scores epilogue (mask ? v/32 : -inf), store bf16.
// EPI 2: store fp32.
// Tile 128x128, BK=32, 4 waves, each wave 64x64 via 4x4 grid of 16x16x32 MFMAs.
template<int AF32, int EPI>
__global__ __launch_bounds__(256) void gemm_nt(
    const void* __restrict__ A0, const void* __restrict__ A1, const void* __restrict__ A2,
    long strideA_bytes,
    const unsigned short* __restrict__ Bmat, long strideB_elems,
    void* __restrict__ Out, long strideOut_bytes,
    const int* __restrict__ mask,
    int M, int N, int K)
{
  __shared__ __attribute__((aligned(16))) unsigned short As[128 * 40];  // +8 pad, keeps 16B align
  __shared__ __attribute__((aligned(16))) unsigned short Bs[128 * 40];
  const int tid = threadIdx.x;
  const int z = blockIdx.z;
  const char* Abase;
  if constexpr (EPI == 0) Abase = (const char*)(z == 0 ? A0 : (z == 1 ? A1 : A2));
  else                    Abase = (const char*)A0 + (size_t)z * strideA_bytes;
  const unsigned short* Bbase = Bmat + (size_t)z * strideB_elems;
  char* Outbase = (char*)Out + (size_t)z * strideOut_bytes;
  const int m0 = blockIdx.y * 128;
  const int n0 = blockIdx.x * 128;

  floatx4 acc[4][4];
  floatx4 zero4 = {0.f, 0.f, 0.f, 0.f};
  #pragma unroll
  for (int a = 0; a < 4; a++)
    #pragma unroll
    for (int b = 0; b < 4; b++) acc[a][b] = zero4;

  const int lane = tid & 63, wave = tid >> 6;
  const int wr = (wave >> 1) * 64, wc = (wave & 1) * 64;
  const int lm = lane & 15, qd = lane >> 4;

  for (int k0 = 0; k0 < K; k0 += 32){
    if constexpr (AF32){
      const float* gA = (const float*)Abase;
      #pragma unroll
      for (int i = 0; i < 4; i++){
        int id = tid + i * 256;               // 1024 float4 chunks
        int r = id >> 3, c = (id & 7) * 4;
        floatx4 f = *(const floatx4*)(gA + (size_t)(m0 + r) * K + k0 + c);
        ushortx4 o;
        o.x = f2bf(f.x); o.y = f2bf(f.y); o.z = f2bf(f.z); o.w = f2bf(f.w);
        *(ushortx4*)&As[r * 40 + c] = o;
      }
    } else {
      const unsigned short* gA = (const unsigned short*)Abase;
      #pragma unroll
      for (int i = 0; i < 2; i++){
        int id = tid + i * 256;               // 512 ushort8 chunks
        int r = id >> 2, c = (id & 3) * 8;
        ushortx8 vv = *(const ushortx8*)(gA + (size_t)(m0 + r) * K + k0 + c);
        *(ushortx8*)&As[r * 40 + c] = vv;
      }
    }
    #pragma unroll
    for (int i = 0; i < 2; i++){
      int id = tid + i * 256;
      int r = id >> 2, c = (id & 3) * 8;
      ushortx8 vv = *(const ushortx8*)(Bbase + (size_t)(n0 + r) * K + k0 + c);
      *(ushortx8*)&Bs[r * 40 + c] = vv;
    }
    __syncthreads();

    short8 af[4], bfr[4];
    #pragma unroll
    for (int mi = 0; mi < 4; mi++)
      af[mi] = *(const short8*)&As[(wr + mi * 16 + lm) * 40 + qd * 8];
    #pragma unroll
    for (int ni = 0; ni < 4; ni++)
      bfr[ni] = *(const short8*)&Bs[(wc + ni * 16 + lm) * 40 + qd * 8];
    #pragma unroll
    for (int mi = 0; mi < 4; mi++)
      #pragma unroll
      for (int ni = 0; ni < 4; ni++)
        acc[mi][ni] = __builtin_amdgcn_mfma_f32_16x16x32_bf16(af[mi], bfr[ni], acc[mi][ni], 0, 0, 0);
    __syncthreads();
  }

  // Epilogue. C/D layout (verified m89/m91): col = lane&15, row = (lane>>4)*4 + i.
  #pragma unroll
  for (int mi = 0; mi < 4; mi++){
    #pragma unroll
    for (int ni = 0; ni < 4; ni++){
      int col = n0 + wc + ni * 16 + lm;
      #pragma unroll
      for (int i = 0; i < 4; i++){
        int row = m0 + wr + mi * 16 + qd * 4 + i;
        float vv = acc[mi][ni][i];
        if constexpr (EPI == 0){
          ((unsigned short*)Outbase)[(size_t)row * N + col] = f2bf(vv);
        } else if constexpr (EPI == 1){
          float s = mask[row * NT + col] ? vv * 0.03125f : -INFINITY;
          ((unsigned short*)Outbase)[(size_t)row * N + col] = f2bf(s);
        } else {
          ((float*)Outbase)[(size_t)row * N + col] = vv;
        }
      }
    }
  }
}

// ---------------- bf16 transpose (per batch): [rows][cols] -> [cols][rows] ----------------
__global__ __launch_bounds__(256) void transpose_bf16(const unsigned short* __restrict__ in,
                                                      unsigned short* __restrict__ out,
                                                      int rows, int cols){
  __shared__ __attribute__((aligned(16))) unsigned short tile[64][72];
  const unsigned short* ib = in + (size_t)blockIdx.z * rows * cols;
  unsigned short* ob = out + (size_t)blockIdx.z * rows * cols;
  int r0 = blockIdx.x * 64;
  int c0 = blockIdx.y * 64;
  int tid = threadIdx.x;
  #pragma unroll
  for (int i = 0; i < 2; i++){
    int id = tid + i * 256;
    int r = id >> 3, c = (id & 7) * 8;
    ushortx8 v = *(const ushortx8*)(ib + (size_t)(r0 + r) * cols + c0 + c);
    *(ushortx8*)&tile[r][c] = v;
  }
  __syncthreads();
  #pragma unroll
  for (int i = 0; i < 2; i++){
    int id = tid + i * 256;
    int r = id >> 3, c = (id & 7) * 8;
    ushortx8 v;
    #pragma unroll
    for (int j = 0; j < 8; j++) v[j] = tile[c + j][r];
    *(ushortx8*)(ob + (size_t)(c0 + r) * rows + r0 + c) = v;
  }
}

// ---------------- row softmax, in place over bf16 scores ----------------
__global__ __launch_bounds__(256) void softmax_rows(unsigned short* __restrict__ S){
  size_t row = blockIdx.x;
  unsigned short* p = S + row * NT;
  int tid = threadIdx.x;
  ushortx8 v = *(const ushortx8*)(p + tid * 8);
  float f[8];
  #pragma unroll
  for (int j = 0; j < 8; j++) f[j] = bf2f(v[j]);
  float mx = f[0];
  #pragma unroll
  for (int j = 1; j < 8; j++) mx = fmaxf(mx, f[j]);
  #pragma unroll
  for (int off = 32; off > 0; off >>= 1) mx = fmaxf(mx, __shfl_xor(mx, off, 64));
  __shared__ float redm[4], reds[4];
  int lane = tid & 63, wv = tid >> 6;
  if (lane == 0) redm[wv] = mx;
  __syncthreads();
  mx = fmaxf(fmaxf(redm[0], redm[1]), fmaxf(redm[2], redm[3]));
  float e[8]; float se = 0.f;
  #pragma unroll
  for (int j = 0; j < 8; j++){ e[j] = __expf(f[j] - mx); se += e[j]; }
  #pragma unroll
  for (int off = 32; off > 0; off >>= 1) se += __shfl_xor(se, off, 64);
  if (lane == 0) reds[wv] = se;
  __syncthreads();
  se = reds[0] + reds[1] + reds[2] + reds[3];
  float inv = 1.f / se;
  ushortx8 o;
  #pragma unroll
  for (int j = 0; j < 8; j++) o[j] = f2bf(e[j] * inv);
  *(ushortx8*)(p + tid * 8) = o;
}

extern "C" void kernel_launch(void* const* d_in, const int* in_sizes, int n_in,
                              void* d_out, int out_size, void* d_ws, size_t ws_size,
                              hipStream_t stream){
  const float* q  = (const float*)d_in[0];
  const float* k  = (const float*)d_in[1];
  const float* v  = (const float*)d_in[2];
  const int* mask = (const int*)d_in[3];
  const float* Wq = (const float*)d_in[4];
  const float* Wk = (const float*)d_in[5];
  const float* Wv = (const float*)d_in[6];

  // Workspace layout (bf16 elements), total ~198 MiB:
  unsigned short* ws   = (unsigned short*)d_ws;
  unsigned short* Wb   = ws;                                   // [3][1024][1024]
  unsigned short* QKVp = Wb + (size_t)3 * NE * NE;             // [3][8*2048][1024]
  unsigned short* Qp   = QKVp;
  unsigned short* Kp   = QKVp + (size_t)NB * NT * NE;
  unsigned short* Vp   = QKVp + (size_t)2 * NB * NT * NE;
  unsigned short* VpT  = QKVp + (size_t)3 * NB * NT * NE;      // [8][1024][2048]
  unsigned short* Sb   = VpT + (size_t)NB * NE * NT;           // [8][2048][2048] bf16

  // 1) weights -> bf16
  convert3<<<dim3(1024, 1, 3), 256, 0, stream>>>(Wq, Wk, Wv, Wb, NE * NE / 4);

  // 2) projections: Q/K/V = x @ W^T  (A fp32 converted in staging; out bf16)
  gemm_nt<1, 0><<<dim3(8, 128, 3), 256, 0, stream>>>(
      q, k, v, 0L,
      Wb, (long)NE * NE,
      QKVp, (long)NB * NT * NE * 2,
      nullptr, NB * NT, NE, NE);

  // 3) V -> V^T per batch (so PV becomes an NT GEMM)
  transpose_bf16<<<dim3(32, 16, 8), 256, 0, stream>>>(Vp, VpT, NT, NE);

  // 4) S = mask ? (Q K^T)/32 : -inf  (bf16)
  gemm_nt<0, 1><<<dim3(16, 16, 8), 256, 0, stream>>>(
      Qp, nullptr, nullptr, (long)NT * NE * 2,
      Kp, (long)NT * NE,
      Sb, (long)NT * NT * 2,
      mask, NT, NT, NE);

  // 5) softmax along s, in place
  softmax_rows<<<dim3(NB * NT), 256, 0, stream>>>(Sb);

  // 6) out = P @ V  (fp32 out)
  gemm_nt<0, 2><<<dim3(8, 16, 8), 256, 0, stream>>>(
      Sb, nullptr, nullptr, (long)NT * NT * 2,
      VpT, (long)NE * NT,
      d_out, (long)NT * NE * 4,
      nullptr, NT, NE, NT);
}

// Round 2
// 544.003 us; speedup vs baseline: 1.2751x; 1.2751x over previous
//
#include <hip/hip_runtime.h>
#include <hip/hip_bf16.h>

// B=8, T=2048, E=1024 single-head attention, bf16 MFMA pipeline, round 2:
// global_load_lds(16B) staging, XOR-swizzled LDS, XCD-aware grid swizzle,
// pre-converted bf16 inputs, bit-packed mask.
typedef __attribute__((ext_vector_type(8))) short short8;
typedef __attribute__((ext_vector_type(8))) unsigned short ushortx8;
typedef __attribute__((ext_vector_type(4))) unsigned short ushortx4;
typedef __attribute__((ext_vector_type(4))) float floatx4;

#define NB 8
#define NT 2048
#define NE 1024

__device__ __forceinline__ unsigned short f2bf(float f){
  unsigned int u = __builtin_bit_cast(unsigned int, f);
  u += 0x7FFFu + ((u >> 16) & 1u);          // RNE; inputs finite
  return (unsigned short)(u >> 16);
}
__device__ __forceinline__ float bf2f(unsigned short h){
  unsigned int u = ((unsigned int)h) << 16;
  return __builtin_bit_cast(float, u);
}

__device__ __forceinline__ void async16(void* lds, const void* g){
  __builtin_amdgcn_global_load_lds(
      (const __attribute__((address_space(1))) unsigned int*)g,
      (__attribute__((address_space(3))) unsigned int*)lds, 16, 0, 0);
}

// ---------------- fp32 -> bf16 convert, 3 sources ----------------
__global__ __launch_bounds__(256) void cvt3(const float* __restrict__ a0,
                                            const float* __restrict__ a1,
                                            const float* __restrict__ a2,
                                            unsigned short* __restrict__ out,
                                            int n4_per){
  const float* src = blockIdx.y == 0 ? a0 : (blockIdx.y == 1 ? a1 : a2);
  unsigned short* dst = out + (size_t)blockIdx.y * (size_t)n4_per * 4;
  int i = blockIdx.x * 256 + threadIdx.x;
  if (i < n4_per){
    floatx4 f = ((const floatx4*)src)[i];
    ushortx4 o;
    o.x = f2bf(f.x); o.y = f2bf(f.y); o.z = f2bf(f.z); o.w = f2bf(f.w);
    *(ushortx4*)(dst + (size_t)i * 4) = o;
  }
}

// ---------------- mask [2048][2048] int32 -> bitmask (512 KB) ----------------
__global__ __launch_bounds__(256) void pack_mask(const int* __restrict__ m,
                                                 unsigned long long* __restrict__ bits){
  int t = blockIdx.x * 256 + threadIdx.x;          // 65536 words
  const int4* p = (const int4*)(m + (size_t)t * 64);
  unsigned long long w = 0;
  #pragma unroll
  for (int jj = 0; jj < 16; jj++){
    int4 v = p[jj];
    w |= (unsigned long long)(v.x != 0) << (jj * 4 + 0);
    w |= (unsigned long long)(v.y != 0) << (jj * 4 + 1);
    w |= (unsigned long long)(v.z != 0) << (jj * 4 + 2);
    w |= (unsigned long long)(v.w != 0) << (jj * 4 + 3);
  }
  bits[t] = w;
}

// ---------------- NT GEMM: C[m,n] = sum_k A[m,k]*B[n,k], all bf16 in ----------------
// Tile 128x128, BK=64, 4 waves (each 64x64 = 4x4 of 16x16x32 MFMAs).
// Staging: global_load_lds dwordx4; LDS slot f(row,c) = row*8 + (c ^ (row&7)) (16B chunks).
// Grid: 1-D, XCD-swizzled: all gx n-tiles of one A-strip land consecutively on one XCD.
// EPI 0: store bf16. EPI 1: mask-bit ? v/32 : -inf, store bf16. EPI 2: store fp32.
template<int EPI>
__global__ __launch_bounds__(256) void gemm_nt(
    const unsigned short* __restrict__ A, long strideA,
    const unsigned short* __restrict__ B, long strideB,
    void* __restrict__ Out, long strideOutBytes,
    const unsigned long long* __restrict__ mbits,
    int K, int gx, int gy)
{
  __shared__ __attribute__((aligned(16))) unsigned short As[128 * 64];  // 16 KB
  __shared__ __attribute__((aligned(16))) unsigned short Bs[128 * 64];  // 16 KB
  const int tid = threadIdx.x;
  const int lane = tid & 63, wave = tid >> 6;

  // XCD-aware decode: L%8 = XCD (HW round-robin heuristic); strip = (y,z) pair.
  int L = blockIdx.x;
  int xcd = L & 7, t = L >> 3;
  int x = t % gx;
  int strip = xcd + ((t / gx) << 3);   // all x-tiles of a strip: same XCD, consecutive
  int y = strip % gy, z = strip / gy;
  const int m0 = y << 7, n0 = x << 7;
  const int Nn = gx << 7;

  const unsigned short* Az = A + (size_t)z * strideA;
  const unsigned short* Bz = B + (size_t)z * strideB;

  // Staging addresses: tile = 1024 slots of 16 B; this wave covers slots
  // wave*256 + i*64 + lane. Inverse swizzle: row = s>>3, chunk = (s&7)^(row&7).
  const char* gA[4]; const char* gB[4]; int lo[4];
  {
    int s0 = (wave << 8) + lane;
    #pragma unroll
    for (int i = 0; i < 4; i++){
      int s = s0 + (i << 6);
      int row = s >> 3;
      int c = (s & 7) ^ (row & 7);
      lo[i] = s << 4;
      gA[i] = (const char*)(Az + (size_t)(m0 + row) * K) + (c << 4);
      gB[i] = (const char*)(Bz + (size_t)(n0 + row) * K) + (c << 4);
    }
  }
  char* AsB = (char*)As;
  char* BsB = (char*)Bs;

  // Fragment-read bases: row = wr+mi*16+lm, chunk h*4+qd at
  // byte row*128 + ((h*4+qd) ^ (lm&7))*16  -> 2-way (free) bank pattern.
  const int lm = lane & 15, qd = lane >> 4;
  const int wr = (wave >> 1) << 6, wc = (wave & 1) << 6;
  const int sw = lm & 7;
  const char* aB0 = AsB + (wr + lm) * 128 + ((qd ^ sw) << 4);
  const char* aB1 = AsB + (wr + lm) * 128 + (((4 + qd) ^ sw) << 4);
  const char* bB0 = BsB + (wc + lm) * 128 + ((qd ^ sw) << 4);
  const char* bB1 = BsB + (wc + lm) * 128 + (((4 + qd) ^ sw) << 4);

  floatx4 acc[4][4];
  floatx4 zero4 = {0.f, 0.f, 0.f, 0.f};
  #pragma unroll
  for (int a = 0; a < 4; a++)
    #pragma unroll
    for (int b = 0; b < 4; b++) acc[a][b] = zero4;

  for (int kk = 0; kk < K; kk += 64){
    #pragma unroll
    for (int i = 0; i < 4; i++){
      async16(AsB + lo[i], gA[i]);
      async16(BsB + lo[i], gB[i]);
      gA[i] += 128; gB[i] += 128;
    }
    __syncthreads();   // drains vmcnt -> LDS valid

    short8 a0[4], a1[4], b0[4], b1[4];
    #pragma unroll
    for (int mi = 0; mi < 4; mi++){
      a0[mi] = *(const short8*)(aB0 + mi * 2048);
      a1[mi] = *(const short8*)(aB1 + mi * 2048);
    }
    #pragma unroll
    for (int ni = 0; ni < 4; ni++){
      b0[ni] = *(const short8*)(bB0 + ni * 2048);
      b1[ni] = *(const short8*)(bB1 + ni * 2048);
    }
    #pragma unroll
    for (int mi = 0; mi < 4; mi++)
      #pragma unroll
      for (int ni = 0; ni < 4; ni++)
        acc[mi][ni] = __builtin_amdgcn_mfma_f32_16x16x32_bf16(a0[mi], b0[ni], acc[mi][ni], 0, 0, 0);
    #pragma unroll
    for (int mi = 0; mi < 4; mi++)
      #pragma unroll
      for (int ni = 0; ni < 4; ni++)
        acc[mi][ni] = __builtin_amdgcn_mfma_f32_16x16x32_bf16(a1[mi], b1[ni], acc[mi][ni], 0, 0, 0);
    __syncthreads();
  }

  // Epilogue. C/D layout: col = lane&15, row = (lane>>4)*4 + i  (m89/m91).
  char* OutZ = (char*)Out + (size_t)z * strideOutBytes;
  if constexpr (EPI == 1){
    int wcol = (n0 + wc) >> 6;
    #pragma unroll
    for (int mi = 0; mi < 4; mi++){
      #pragma unroll
      for (int i = 0; i < 4; i++){
        int row = m0 + wr + mi * 16 + qd * 4 + i;
        unsigned long long w = mbits[(size_t)row * (NT / 64) + wcol];
        unsigned short* po = (unsigned short*)OutZ + (size_t)row * Nn + n0 + wc;
        #pragma unroll
        for (int ni = 0; ni < 4; ni++){
          float vv = acc[mi][ni][i];
          float s = ((w >> (ni * 16 + lm)) & 1ull) ? vv * 0.03125f : -INFINITY;
          po[ni * 16 + lm] = f2bf(s);
        }
      }
    }
  } else {
    #pragma unroll
    for (int mi = 0; mi < 4; mi++){
      #pragma unroll
      for (int i = 0; i < 4; i++){
        int row = m0 + wr + mi * 16 + qd * 4 + i;
        #pragma unroll
        for (int ni = 0; ni < 4; ni++){
          int col = n0 + wc + ni * 16 + lm;
          float vv = acc[mi][ni][i];
          if constexpr (EPI == 0)
            ((unsigned short*)OutZ)[(size_t)row * Nn + col] = f2bf(vv);
          else
            ((float*)OutZ)[(size_t)row * Nn + col] = vv;
        }
      }
    }
  }
}

// ---------------- bf16 transpose (per batch): [rows][cols] -> [cols][rows] ----------------
__global__ __launch_bounds__(256) void transpose_bf16(const unsigned short* __restrict__ in,
                                                      unsigned short* __restrict__ out,
                                                      int rows, int cols){
  __shared__ __attribute__((aligned(16))) unsigned short tile[64][72];
  const unsigned short* ib = in + (size_t)blockIdx.z * rows * cols;
  unsigned short* ob = out + (size_t)blockIdx.z * rows * cols;
  int r0 = blockIdx.x * 64;
  int c0 = blockIdx.y * 64;
  int tid = threadIdx.x;
  #pragma unroll
  for (int i = 0; i < 2; i++){
    int id = tid + i * 256;
    int r = id >> 3, c = (id & 7) * 8;
    ushortx8 v = *(const ushortx8*)(ib + (size_t)(r0 + r) * cols + c0 + c);
    *(ushortx8*)&tile[r][c] = v;
  }
  __syncthreads();
  #pragma unroll
  for (int i = 0; i < 2; i++){
    int id = tid + i * 256;
    int r = id >> 3, c = (id & 7) * 8;
    ushortx8 v;
    #pragma unroll
    for (int j = 0; j < 8; j++) v[j] = tile[c + j][r];
    *(ushortx8*)(ob + (size_t)(c0 + r) * rows + r0 + c) = v;
  }
}

// ---------------- row softmax, in place over bf16 scores ----------------
__global__ __launch_bounds__(256) void softmax_rows(unsigned short* __restrict__ S){
  size_t row = blockIdx.x;
  unsigned short* p = S + row * NT;
  int tid = threadIdx.x;
  ushortx8 v = *(const ushortx8*)(p + tid * 8);
  float f[8];
  #pragma unroll
  for (int j = 0; j < 8; j++) f[j] = bf2f(v[j]);
  float mx = f[0];
  #pragma unroll
  for (int j = 1; j < 8; j++) mx = fmaxf(mx, f[j]);
  #pragma unroll
  for (int off = 32; off > 0; off >>= 1) mx = fmaxf(mx, __shfl_xor(mx, off, 64));
  __shared__ float redm[4], reds[4];
  int lane = tid & 63, wv = tid >> 6;
  if (lane == 0) redm[wv] = mx;
  __syncthreads();
  mx = fmaxf(fmaxf(redm[0], redm[1]), fmaxf(redm[2], redm[3]));
  float e[8]; float se = 0.f;
  #pragma unroll
  for (int j = 0; j < 8; j++){ e[j] = __expf(f[j] - mx); se += e[j]; }
  #pragma unroll
  for (int off = 32; off > 0; off >>= 1) se += __shfl_xor(se, off, 64);
  if (lane == 0) reds[wv] = se;
  __syncthreads();
  se = reds[0] + reds[1] + reds[2] + reds[3];
  float inv = 1.f / se;
  ushortx8 o;
  #pragma unroll
  for (int j = 0; j < 8; j++) o[j] = f2bf(e[j] * inv);
  *(ushortx8*)(p + tid * 8) = o;
}

extern "C" void kernel_launch(void* const* d_in, const int* in_sizes, int n_in,
                              void* d_out, int out_size, void* d_ws, size_t ws_size,
                              hipStream_t stream){
  const float* q  = (const float*)d_in[0];
  const float* k  = (const float*)d_in[1];
  const float* v  = (const float*)d_in[2];
  const int* mask = (const int*)d_in[3];
  const float* Wq = (const float*)d_in[4];
  const float* Wk = (const float*)d_in[5];
  const float* Wv = (const float*)d_in[6];

  const size_t BTE = (size_t)NB * NT * NE;     // 16,777,216
  unsigned short* ws   = (unsigned short*)d_ws;
  unsigned short* QKVp = ws;                                    // [3][B*T][E]
  unsigned short* VpT  = ws + 3 * BTE;                          // [B][E][T]
  unsigned short* Sb   = ws + 3 * BTE + BTE;                    // [B][T][T]
  unsigned short* Qin  = ws + 3 * BTE;                          // aliases VpT+Sb (3*BTE)
  unsigned short* Wb   = ws + 3 * BTE + BTE + (size_t)NB * NT * NT;  // [3][E][E]
  unsigned long long* mbits = (unsigned long long*)(Wb + (size_t)3 * NE * NE);

  unsigned short* Qp = QKVp;
  unsigned short* Kp = QKVp + BTE;
  unsigned short* Vp = QKVp + 2 * BTE;

  // 1) fp32 -> bf16: inputs q,k,v (Qin aliases the region later used by VpT|Sb)
  cvt3<<<dim3(16384, 3), 256, 0, stream>>>(q, k, v, Qin, (int)(BTE / 4));
  // 2) weights -> bf16
  cvt3<<<dim3(1024, 3), 256, 0, stream>>>(Wq, Wk, Wv, Wb, NE * NE / 4);
  // 3) mask -> bitmask
  pack_mask<<<256, 256, 0, stream>>>(mask, mbits);

  // 4) projections: [3 x] (16384 x 1024 x 1024); gx=8, gy=128, gz=3
  gemm_nt<0><<<3072, 256, 0, stream>>>(
      Qin, (long)BTE, Wb, (long)NE * NE,
      QKVp, (long)BTE * 2, nullptr, NE, 8, 128);

  // 5) V -> V^T per batch (overwrites Qin's q-part, no longer needed)
  transpose_bf16<<<dim3(32, 16, 8), 256, 0, stream>>>(Vp, VpT, NT, NE);

  // 6) S = mask ? QK^T/32 : -inf; gx=16, gy=16, gz=8
  gemm_nt<1><<<2048, 256, 0, stream>>>(
      Qp, (long)NT * NE, Kp, (long)NT * NE,
      Sb, (long)NT * NT * 2, mbits, NE, 16, 16);

  // 7) softmax rows, in place
  softmax_rows<<<dim3(NB * NT), 256, 0, stream>>>(Sb);

  // 8) O = P V; gx=8, gy=16, gz=8, fp32 out
  gemm_nt<2><<<1024, 256, 0, stream>>>(
      Sb, (long)NT * NT, VpT, (long)NE * NT,
      d_out, (long)NT * NE * 4, nullptr, NT, 8, 16);
}